// Round 6
// baseline (43.299 us; speedup 1.0000x reference)
//
#include <hip/hip_runtime.h>
#include <hip/hip_bf16.h>
#include <math.h>

namespace {

constexpr int L   = 64;    // steps
constexpr int NH  = 256;   // nhid
constexpr int NC  = 64;    // cache_N
constexpr int BSZ = 32;

typedef float f32x16 __attribute__((ext_vector_type(16)));
typedef short bf16x8 __attribute__((ext_vector_type(8)));   // 8 bf16 in 4 VGPRs

// Split 8 fp32 into hi/lo bf16x8: x = hi + lo + O(2^-18 x). (validated R3/R5)
__device__ inline void split8(const float4 x0, const float4 x1,
                              bf16x8& hi, bf16x8& lo) {
  float f[8];
  *(float4*)(f)     = x0;
  *(float4*)(f + 4) = x1;
#pragma unroll
  for (int q = 0; q < 8; ++q) {
    const __hip_bfloat16 h = __float2bfloat16(f[q]);        // RNE
    unsigned short hu;
    __builtin_memcpy(&hu, &h, 2);
    const float hf = __builtin_bit_cast(float, (unsigned)hu << 16);
    const __hip_bfloat16 l = __float2bfloat16(f[q] - hf);   // exact residual, RNE
    unsigned short lu;
    __builtin_memcpy(&lu, &l, 2);
    hi[q] = (short)hu;
    lo[q] = (short)lu;
  }
}

// global -> LDS direct (16B per lane, linear dest = base + lane*16)
__device__ inline void gl16(const void* g, void* l) {
  __builtin_amdgcn_global_load_lds(
      (const __attribute__((address_space(1))) unsigned*)(g),
      (__attribute__((address_space(3))) unsigned*)(l), 16, 0, 0);
}

// Block = 256 thr = 4 waves, handles (b, 2 n). Wave w owns (n = np*2 + (w>>1),
// jt = w&1): C strip rows 0..63 x cols jt*32..+32. Q_b staged once per block
// into LDS as split-bf16 fragments (lane-linear, conflict-free); K streamed
// via wave-private global_load_lds double-buffered 2KB chunks (coalesced,
// full-line granules). No barriers in the main loop.
__global__ __launch_bounds__(256, 2) void attmax_mfma(
    const float* __restrict__ query,   // (1, 64, 32, 256)
    const float* __restrict__ keys,    // (64, 32, 16384)
    float* __restrict__ out)           // out[b*64+n] = att
{
  // LDS map: [0,32K) Qhi frags | [32K,64K) Qlo frags | [64K,80K) Sraw/K-chunks
  __shared__ __align__(16) char lds[80 * 1024];
  short* Qhi  = (short*)lds;                  // slot ((it*16+kc)*64+lane)*8
  short* Qlo  = (short*)(lds + 32 * 1024);
  float* Sraw = (float*)(lds + 64 * 1024);    // prologue scratch [16][256]
  char*  Kch  = lds + 64 * 1024;              // per-wave 4KB (2 bufs x 2KB)

  // XCD-affine: blocks sharing b land on the same XCD (X%8 == b%8).
  const unsigned X = blockIdx.x;              // 0..1023
  const int b  = ((X >> 8) << 3) | (X & 7);   // 0..31
  const int np = (X >> 3) & 31;               // n-pair 0..31

  const int tid  = threadIdx.x;
  const int w    = tid >> 6;                  // wave 0..3
  const int lane = tid & 63;
  const int n    = np * 2 + (w >> 1);
  const int jt   = w & 1;

  // ---- Prologue: Q_b -> split-bf16 fragments in LDS (4 pieces of 16 rows) ---
  for (int p = 0; p < 4; ++p) {
    // coalesced load rows p*16..+15 into Sraw
#pragma unroll
    for (int q = 0; q < 4; ++q) {
      const int s   = tid + q * 256;          // 0..1023 float4 slots
      const int row = s >> 6, c4 = s & 63;
      *(float4*)&Sraw[row * 256 + c4 * 4] =
          *(const float4*)&query[(((size_t)(p * 16 + row)) * BSZ + b) * NH + c4 * 4];
    }
    __syncthreads();
    // build frags for it = p>>1, fr-half = p&1; kc range split across waves
    if (((lane >> 4) & 1) == (p & 1)) {
      const int it = p >> 1;
      const int rl = lane & 15;               // row-local in Sraw
#pragma unroll
      for (int kk = 0; kk < 4; ++kk) {
        const int kc = w * 4 + kk;
        const float* s8 = &Sraw[rl * 256 + kc * 16 + (lane >> 5) * 8];
        bf16x8 hi, lo;
        split8(*(const float4*)s8, *(const float4*)(s8 + 4), hi, lo);
        const int slot = ((it * 16 + kc) * 64 + lane) * 8;
        *(bf16x8*)&Qhi[slot] = hi;
        *(bf16x8*)&Qlo[slot] = lo;
      }
    }
    __syncthreads();
  }

  // ---- Main loop: wave-private K chunks, barrier-free ----
  // wave's 32 K rows: keys[(n*32+b)*16384 + (jt*32 + r)*256 + k]
  const float* kb = keys + ((size_t)n * BSZ + b) * (size_t)(L * NH)
                  + (size_t)jt * 32 * NH;
  char* mybuf = Kch + w * 4096;

  // STAGE chunk kc into buf: LDS image [32 rows][64B] row-major.
  // Source: 4 lanes x 16B per row (full 64B run), rows 1KB apart.
#define STAGE(buf, kc)                                                        \
  do {                                                                        \
    const float* s0 = kb + (size_t)(lane >> 2) * NH + (kc) * 16 + (lane & 3) * 4; \
    gl16(s0, mybuf + (buf) * 2048);                                           \
    gl16(s0 + 16 * NH, mybuf + (buf) * 2048 + 1024);                          \
  } while (0)

  f32x16 acc[2];
#pragma unroll
  for (int it = 0; it < 2; ++it)
#pragma unroll
    for (int e = 0; e < 16; ++e) acc[it][e] = 0.f;

  STAGE(0, 0);

  int buf = 0;
#pragma unroll
  for (int kc = 0; kc < 16; ++kc) {
    if (kc < 15) {
      STAGE(buf ^ 1, kc + 1);
      asm volatile("s_waitcnt vmcnt(2)" ::: "memory");  // chunk kc landed
    } else {
      asm volatile("s_waitcnt vmcnt(0)" ::: "memory");
    }
    __builtin_amdgcn_sched_barrier(0);

    const float* b8 = (const float*)(mybuf + buf * 2048 + (lane & 31) * 64
                                     + (lane >> 5) * 32);
    bf16x8 bh, bl;
    split8(*(const float4*)b8, *(const float4*)(b8 + 4), bh, bl);

#pragma unroll
    for (int it = 0; it < 2; ++it) {
      const int slot = ((it * 16 + kc) * 64 + lane) * 8;
      const bf16x8 ah = *(const bf16x8*)&Qhi[slot];
      const bf16x8 al = *(const bf16x8*)&Qlo[slot];
      acc[it] = __builtin_amdgcn_mfma_f32_32x32x16_bf16(al, bh, acc[it], 0, 0, 0);
      acc[it] = __builtin_amdgcn_mfma_f32_32x32x16_bf16(ah, bl, acc[it], 0, 0, 0);
      acc[it] = __builtin_amdgcn_mfma_f32_32x32x16_bf16(ah, bh, acc[it], 0, 0, 0);
    }
    buf ^= 1;
  }
#undef STAGE

  // ---- Reduce: wave max, then pair the two jt-waves of each n ----
  float m = -INFINITY;
#pragma unroll
  for (int it = 0; it < 2; ++it)
#pragma unroll
    for (int e = 0; e < 16; ++e) m = fmaxf(m, acc[it][e]);
#pragma unroll
  for (int off = 1; off < 64; off <<= 1)
    m = fmaxf(m, __shfl_xor(m, off, 64));

  __syncthreads();                 // all waves done with Q/chunk regions
  float* wm = (float*)lds;
  if (lane == 0) wm[w] = m;
  __syncthreads();
  if (lane == 0 && (w & 1) == 0)
    out[(size_t)b * NC + n] = fmaxf(wm[w], wm[w + 1]);
}

// One block (64 lanes) per batch b: 8 rounds of argmax with lowest-index
// tie-break (matches jax.lax.top_k stability). Indices written as floats.
__global__ __launch_bounds__(64) void topk_kernel(float* __restrict__ out) {
  const int b = blockIdx.x;
  const int l = threadIdx.x;
  float v = out[b * NC + l];
#pragma unroll
  for (int k = 0; k < 8; ++k) {
    float bv = v;
    int bi = l;
#pragma unroll
    for (int off = 1; off < 64; off <<= 1) {
      const float ov = __shfl_xor(bv, off, 64);
      const int oi = __shfl_xor(bi, off, 64);
      if (ov > bv || (ov == bv && oi < bi)) { bv = ov; bi = oi; }
    }
    if (l == 0) out[BSZ * NC + k * BSZ + b] = (float)bi;  // (topk, bsz) layout
    if (l == bi) v = -INFINITY;
  }
}

}  // namespace

extern "C" void kernel_launch(void* const* d_in, const int* in_sizes, int n_in,
                              void* d_out, int out_size, void* d_ws, size_t ws_size,
                              hipStream_t stream) {
  const float* query = (const float*)d_in[0];
  const float* keys  = (const float*)d_in[1];
  // d_in[2] (values) is dead code in the max_pooling branch — never read.
  float* out = (float*)d_out;

  attmax_mfma<<<dim3(1024), dim3(256), 0, stream>>>(query, keys, out);
  topk_kernel<<<dim3(BSZ), dim3(64), 0, stream>>>(out);
}

// Round 7
// 40.296 us; speedup vs baseline: 1.0745x; 1.0745x over previous
//
#include <hip/hip_runtime.h>
#include <hip/hip_bf16.h>
#include <math.h>

namespace {

constexpr int L   = 64;    // steps
constexpr int NH  = 256;   // nhid
constexpr int NC  = 64;    // cache_N
constexpr int BSZ = 32;

typedef float f32x16 __attribute__((ext_vector_type(16)));
typedef short bf16x8 __attribute__((ext_vector_type(8)));   // 8 bf16 in 4 VGPRs

// Split 8 fp32 into hi/lo bf16x8: x = hi + lo + O(2^-18 x). (validated R3-R6)
__device__ inline void split8(const float4 x0, const float4 x1,
                              bf16x8& hi, bf16x8& lo) {
  float f[8];
  *(float4*)(f)     = x0;
  *(float4*)(f + 4) = x1;
#pragma unroll
  for (int q = 0; q < 8; ++q) {
    const __hip_bfloat16 h = __float2bfloat16(f[q]);        // RNE
    unsigned short hu;
    __builtin_memcpy(&hu, &h, 2);
    const float hf = __builtin_bit_cast(float, (unsigned)hu << 16);
    const __hip_bfloat16 l = __float2bfloat16(f[q] - hf);   // exact residual, RNE
    unsigned short lu;
    __builtin_memcpy(&lu, &l, 2);
    hi[q] = (short)hu;
    lo[q] = (short)lu;
  }
}

// global -> LDS direct: per-lane 16B, dest = uniform base + lane*16 (linear)
__device__ inline void gl16(const void* g, void* l) {
  __builtin_amdgcn_global_load_lds(
      (const __attribute__((address_space(1))) unsigned*)(g),
      (__attribute__((address_space(3))) unsigned*)(l), 16, 0, 0);
}

// ---- Kernel 0: pre-split Q into fragment-layout hi/lo bf16 in d_ws ----
// ws[b] = 64KB: [0,32K) hi slots, [32K,64K) lo slots; slot s (16B) holds
// frag for it=s>>10, kc=(s>>6)&15, lane=s&63 (row it*32+(lane&31),
// k = kc*16 + (lane>>5)*8 .. +8).
__global__ __launch_bounds__(256) void qsplit_kernel(
    const float* __restrict__ query, char* __restrict__ ws) {
  const int b   = blockIdx.x;
  const int tid = threadIdx.x;
  char* wb = ws + (size_t)b * 65536;
#pragma unroll
  for (int rr = 0; rr < 8; ++rr) {
    const int s  = tid + rr * 256;          // 0..2047
    const int it = s >> 10;
    const int kc = (s >> 6) & 15;
    const int sl = s & 63;
    const int row = it * 32 + (sl & 31);
    const int kof = kc * 16 + (sl >> 5) * 8;
    const float* src = query + ((size_t)row * BSZ + b) * NH + kof;
    bf16x8 hi, lo;
    split8(*(const float4*)src, *(const float4*)(src + 4), hi, lo);
    *(bf16x8*)(wb + (size_t)s * 16)         = hi;
    *(bf16x8*)(wb + 32768 + (size_t)s * 16) = lo;
  }
}

// ---- Kernel 1: block = 512 thr = 8 waves, owns (b, 4 n). Wave w owns
// (n = ng*4 + (w>>1), jt = w&1): C strip 64 x 32. Q frags copied from ws
// into LDS (contiguous gl16, one barrier); K streamed register-direct with
// depth-2 pipeline (R5 pattern). No main-loop barriers.
__global__ __launch_bounds__(512, 4) void attmax_mfma(
    const float* __restrict__ keys,    // (64, 32, 16384)
    const char* __restrict__ ws,       // Q frag images
    float* __restrict__ out)           // out[b*64+n] = att
{
  __shared__ __align__(16) char qlds[64 * 1024];  // hi [0,32K), lo [32K,64K)
  __shared__ float wm[8];
  const short* Qhi = (const short*)qlds;
  const short* Qlo = (const short*)(qlds + 32768);

  // grid 512: X = ng*32 + b  -> same-b blocks share XCD (X%8 == b%8)
  const unsigned X = blockIdx.x;
  const int b  = X & 31;
  const int ng = X >> 5;

  const int tid  = threadIdx.x;
  const int w    = tid >> 6;          // wave 0..7
  const int lane = tid & 63;
  const int n    = ng * 4 + (w >> 1);
  const int jt   = w & 1;

  // ---- Copy Q frag image (64KB) from ws: 8 rounds x 8 waves x 1KB ----
  {
    const char* src = ws + (size_t)b * 65536;
#pragma unroll
    for (int q = 0; q < 8; ++q) {
      const int off = (q * 8 + w) * 1024;
      gl16(src + off + lane * 16, qlds + off);
    }
  }
  __syncthreads();   // includes vmcnt(0) drain of the lds-DMA

  // ---- Main loop ----
  // wave's K rows: keys[(n*32+b)*16384 + (jt*32 + (lane&31))*256 + k],
  // k-slice (lane>>5)*8 within each 16-float kc chunk.
  const float* kp = keys + ((size_t)n * BSZ + b) * (size_t)(L * NH)
                  + (size_t)(jt * 32 + (lane & 31)) * NH + (lane >> 5) * 8;

  f32x16 acc[2];
#pragma unroll
  for (int it = 0; it < 2; ++it)
#pragma unroll
    for (int e = 0; e < 16; ++e) acc[it][e] = 0.f;

  float4 bufA[2], bufB[2];

#define LOAD_K(buf, kc)                                  \
  do {                                                   \
    const float* p0 = kp + (kc) * 16;                    \
    (buf)[0] = *(const float4*)(p0);                     \
    (buf)[1] = *(const float4*)(p0 + 4);                 \
  } while (0)

#define COMPUTE(buf, kc)                                                      \
  do {                                                                        \
    bf16x8 bh, bl;                                                            \
    split8((buf)[0], (buf)[1], bh, bl);                                       \
    _Pragma("unroll")                                                         \
    for (int it = 0; it < 2; ++it) {                                          \
      const int slot = ((it * 16 + (kc)) * 64 + lane) * 8;                    \
      const bf16x8 ah = *(const bf16x8*)&Qhi[slot];                           \
      const bf16x8 al = *(const bf16x8*)&Qlo[slot];                           \
      acc[it] = __builtin_amdgcn_mfma_f32_32x32x16_bf16(al, bh, acc[it], 0, 0, 0); \
      acc[it] = __builtin_amdgcn_mfma_f32_32x32x16_bf16(ah, bl, acc[it], 0, 0, 0); \
      acc[it] = __builtin_amdgcn_mfma_f32_32x32x16_bf16(ah, bh, acc[it], 0, 0, 0); \
    }                                                                         \
  } while (0)

  LOAD_K(bufA, 0);
#pragma unroll
  for (int kc = 0; kc < 16; kc += 2) {
    if (kc + 1 < 16) LOAD_K(bufB, kc + 1);
    COMPUTE(bufA, kc);
    if (kc + 2 < 16) LOAD_K(bufA, kc + 2);
    COMPUTE(bufB, kc + 1);
  }
#undef LOAD_K
#undef COMPUTE

  // ---- Reduce: wave max, then pair the two jt-waves of each n ----
  float m = -INFINITY;
#pragma unroll
  for (int it = 0; it < 2; ++it)
#pragma unroll
    for (int e = 0; e < 16; ++e) m = fmaxf(m, acc[it][e]);
#pragma unroll
  for (int off = 1; off < 64; off <<= 1)
    m = fmaxf(m, __shfl_xor(m, off, 64));

  if (lane == 0) wm[w] = m;
  __syncthreads();
  if (lane == 0 && (w & 1) == 0)
    out[(size_t)b * NC + n] = fmaxf(wm[w], wm[w + 1]);
}

// One block (64 lanes) per batch b: 8 rounds of argmax with lowest-index
// tie-break (matches jax.lax.top_k stability). Indices written as floats.
__global__ __launch_bounds__(64) void topk_kernel(float* __restrict__ out) {
  const int b = blockIdx.x;
  const int l = threadIdx.x;
  float v = out[b * NC + l];
#pragma unroll
  for (int k = 0; k < 8; ++k) {
    float bv = v;
    int bi = l;
#pragma unroll
    for (int off = 1; off < 64; off <<= 1) {
      const float ov = __shfl_xor(bv, off, 64);
      const int oi = __shfl_xor(bi, off, 64);
      if (ov > bv || (ov == bv && oi < bi)) { bv = ov; bi = oi; }
    }
    if (l == 0) out[BSZ * NC + k * BSZ + b] = (float)bi;  // (topk, bsz) layout
    if (l == bi) v = -INFINITY;
  }
}

}  // namespace

extern "C" void kernel_launch(void* const* d_in, const int* in_sizes, int n_in,
                              void* d_out, int out_size, void* d_ws, size_t ws_size,
                              hipStream_t stream) {
  const float* query = (const float*)d_in[0];
  const float* keys  = (const float*)d_in[1];
  // d_in[2] (values) is dead code in the max_pooling branch — never read.
  float* out = (float*)d_out;
  char*  ws  = (char*)d_ws;   // uses 2 MB of workspace for Q frag images

  qsplit_kernel<<<dim3(BSZ), dim3(256), 0, stream>>>(query, ws);
  attmax_mfma<<<dim3(512), dim3(512), 0, stream>>>(keys, ws, out);
  topk_kernel<<<dim3(BSZ), dim3(64), 0, stream>>>(out);
}